// Round 5
// baseline (521.760 us; speedup 1.0000x reference)
//
#include <hip/hip_runtime.h>
#include <hip/hip_bf16.h>

#define N_USERS 100000
#define N_ITEMS 50000
#define N_NODES 150000
#define DIM 64
#define N_EDGES 4000000
#define BATCH 4096

#define NBKT 256
#define BW 587           // nodes per bucket; 256*587 = 150272 >= 150000
#define STRIDE 18432     // tmp records per bucket (max bucket ~16.3K at 19 sigma)
#define CAP 24           // LDS staging slots per bucket in pass A
#define PA_EDGES 4096    // edges per block in pass A

// ---------------- bf16 helpers ----------------
__device__ __forceinline__ float blo(unsigned int u) { return __uint_as_float(u << 16); }
__device__ __forceinline__ float bhi(unsigned int u) { return __uint_as_float(u & 0xffff0000u); }
__device__ __forceinline__ unsigned int f2b(float f) {  // RTNE
    unsigned int x = __float_as_uint(f);
    return (x + 0x7fffu + ((x >> 16) & 1u)) >> 16;
}
__device__ __forceinline__ unsigned int pack2(float a, float b) {
    return f2b(a) | (f2b(b) << 16);
}
__device__ __forceinline__ int2 nt_load_int2(const int2* p) {
    unsigned long long v = __builtin_nontemporal_load((const unsigned long long*)p);
    return make_int2((int)(unsigned int)v, (int)(v >> 32));
}

// fp32 tables -> bf16 concat table (single launch)
__global__ void k_cvt(const float* __restrict__ uemb, const float* __restrict__ iemb,
                      ushort* __restrict__ out) {
    int i = (blockIdx.x * blockDim.x + threadIdx.x) * 4;
    if (i >= N_NODES * DIM) return;
    const float* srcp = (i < N_USERS * DIM) ? (uemb + i) : (iemb + (i - N_USERS * DIM));
    float4 v;
    v.x = __builtin_nontemporal_load(srcp + 0);
    v.y = __builtin_nontemporal_load(srcp + 1);
    v.z = __builtin_nontemporal_load(srcp + 2);
    v.w = __builtin_nontemporal_load(srcp + 3);
    *(uint2*)(out + i) = make_uint2(pack2(v.x, v.y), pack2(v.z, v.w));
}

// ---------------- pass A: LDS-staged partition into fixed-stride buckets ----------------
__global__ void k_partition(const int* __restrict__ src, const int* __restrict__ dst,
                            const float* __restrict__ vals, int* __restrict__ gcur,
                            int2* __restrict__ tmp) {
    __shared__ int cnt[NBKT];
    __shared__ int2 buf[NBKT][CAP];  // 48 KB
    __shared__ int gbase_s[NBKT];
    __shared__ int pfx[NBKT + 1];
    __shared__ int wsum[4];
    int t = threadIdx.x;
    cnt[t] = 0;
    __syncthreads();
    size_t base = (size_t)blockIdx.x * PA_EDGES;
#pragma unroll
    for (int it = 0; it < PA_EDGES / 256; it++) {
        size_t i = base + (size_t)it * 256 + t;
        if (i < N_EDGES) {
            int d = __builtin_nontemporal_load(dst + i);
            int s = __builtin_nontemporal_load(src + i);
            float v = __builtin_nontemporal_load(vals + i);
            int b = d / BW;
            int local = d - b * BW;
            int2 rec = make_int2((s << 10) | local, __float_as_int(v));
            int slot = atomicAdd(&cnt[b], 1);
            if (slot < CAP) buf[b][slot] = rec;
            else {  // rare overflow path
                int p = atomicAdd(&gcur[b], 1);
                unsigned long long rv = (unsigned int)rec.x | ((unsigned long long)(unsigned int)rec.y << 32);
                __builtin_nontemporal_store(rv, (unsigned long long*)&tmp[(size_t)b * STRIDE + p]);
            }
        }
    }
    __syncthreads();
    // cooperative drain: per-bin base + LDS prefix over capped counts
    int c = min(cnt[t], CAP);
    int p = (c > 0) ? atomicAdd(&gcur[t], c) : 0;
    gbase_s[t] = p;
    int lane = t & 63, w = t >> 6;
    int incl = c;
    for (int o = 1; o < 64; o <<= 1) {
        int y = __shfl_up(incl, o);
        if (lane >= o) incl += y;
    }
    if (lane == 63) wsum[w] = incl;
    __syncthreads();
    int woff = 0;
    for (int j = 0; j < w; j++) woff += wsum[j];
    int excl = woff + incl - c;
    pfx[t] = excl;
    if (t == 255) pfx[256] = excl + c;
    __syncthreads();
    int total = pfx[256];
    for (int f = t; f < total; f += 256) {
        int lo = 0, hi = 255;
        while (lo < hi) {  // largest bin with pfx[bin] <= f
            int mid = (lo + hi + 1) >> 1;
            if (pfx[mid] <= f) lo = mid; else hi = mid - 1;
        }
        int slot = f - pfx[lo];
        int2 rec = buf[lo][slot];
        unsigned long long rv = (unsigned int)rec.x | ((unsigned long long)(unsigned int)rec.y << 32);
        __builtin_nontemporal_store(rv, (unsigned long long*)&tmp[(size_t)lo * STRIDE + gbase_s[lo] + slot]);
    }
}

// scan 256 bucket sizes (in gcur) -> bucket_ptr[257] (dense fin layout)
__global__ void k_bscan(const int* __restrict__ gcur, int* __restrict__ bucket_ptr) {
    int lane = threadIdx.x;  // 64 threads
    int carry = 0;
    for (int c = 0; c < 4; c++) {
        int i = c * 64 + lane;
        int x = gcur[i];
        int incl = x;
        for (int off = 1; off < 64; off <<= 1) {
            int y = __shfl_up(incl, off);
            if (lane >= off) incl += y;
        }
        bucket_ptr[i] = carry + incl - x;
        carry += __shfl(incl, 63);
    }
    if (lane == 0) bucket_ptr[NBKT] = N_EDGES;
}

// ---------------- pass B: sort within bucket (LDS hist + scan), emit dense CSR ----------------
__global__ void k_bsort(const int2* __restrict__ tmp, const int* __restrict__ gcur,
                        const int* __restrict__ bucket_ptr, int* __restrict__ row_ptr,
                        int2* __restrict__ fin) {
    __shared__ int cnt[BW + 64];
    __shared__ int off[BW + 64];
    int b = blockIdx.x, t = threadIdx.x;  // 512 threads
    int node0 = b * BW;
    int nodes = min(BW, N_NODES - node0);
    int gbase = bucket_ptr[b];
    int count = gcur[b];
    const int2* tb = tmp + (size_t)b * STRIDE;
    for (int i = t; i < BW + 64; i += 512) cnt[i] = 0;
    __syncthreads();
    for (int e = t; e < count; e += 512) atomicAdd(&cnt[tb[e].x & 1023], 1);
    __syncthreads();
    if (t < 64) {
        int lane = t;
        int carry = 0;
        for (int c = 0; c < 10; c++) {
            int i = c * 64 + lane;
            int x = (i < nodes) ? cnt[i] : 0;
            int incl = x;
            for (int o = 1; o < 64; o <<= 1) {
                int y = __shfl_up(incl, o);
                if (lane >= o) incl += y;
            }
            if (i <= nodes) off[i] = carry + incl - x;
            carry += __shfl(incl, 63);
        }
    }
    __syncthreads();
    for (int i = t; i <= nodes; i += 512)
        if (node0 + i <= N_NODES) row_ptr[node0 + i] = gbase + off[i];
    __syncthreads();
    for (int e = t; e < count; e += 512) {
        int2 r = tb[e];
        int local = r.x & 1023;
        int pos = gbase + atomicAdd(&off[local], 1);
        unsigned long long rv = (unsigned int)(r.x >> 10) | ((unsigned long long)(unsigned int)r.y << 32);
        __builtin_nontemporal_store(rv, (unsigned long long*)&fin[pos]);
    }
}

// ---------------- bf16 SpMM: one wave per dst node, 8 groups x 8 lanes ----------------
#define SPMM_EDGE(r)                                                              \
    {                                                                             \
        const uint4 u = *(const uint4*)(ein + (size_t)(r).x * DIM + q * 8);       \
        float v = __int_as_float((r).y);                                          \
        acc[0] += v * blo(u.x); acc[1] += v * bhi(u.x);                           \
        acc[2] += v * blo(u.y); acc[3] += v * bhi(u.y);                           \
        acc[4] += v * blo(u.z); acc[5] += v * bhi(u.z);                           \
        acc[6] += v * blo(u.w); acc[7] += v * bhi(u.w);                           \
    }

__global__ void k_spmm16(const ushort* __restrict__ ein, ushort* __restrict__ eout,
                         const int* __restrict__ row_ptr, const int2* __restrict__ fin) {
    int wave = (blockIdx.x * blockDim.x + threadIdx.x) >> 6;
    if (wave >= N_NODES) return;
    int lane = threadIdx.x & 63;
    int g = lane >> 3;  // edge group 0..7
    int q = lane & 7;   // 8 bf16 dims per lane
    int start = row_ptr[wave], end = row_ptr[wave + 1];
    float acc[8];
#pragma unroll
    for (int j = 0; j < 8; j++) acc[j] = 0.f;
    int e = start + g;
    for (; e + 8 < end; e += 16) {
        int2 r0 = nt_load_int2(&fin[e]);
        int2 r1 = nt_load_int2(&fin[e + 8]);
        SPMM_EDGE(r0);
        SPMM_EDGE(r1);
    }
    for (; e < end; e += 8) {
        int2 r0 = nt_load_int2(&fin[e]);
        SPMM_EDGE(r0);
    }
#pragma unroll
    for (int off = 8; off < 64; off <<= 1) {
#pragma unroll
        for (int j = 0; j < 8; j++) acc[j] += __shfl_xor(acc[j], off);
    }
    if (lane < 8) {
        unsigned long long lo = (unsigned long long)pack2(acc[0], acc[1]) |
                                ((unsigned long long)pack2(acc[2], acc[3]) << 32);
        unsigned long long hi = (unsigned long long)pack2(acc[4], acc[5]) |
                                ((unsigned long long)pack2(acc[6], acc[7]) << 32);
        unsigned long long* op = (unsigned long long*)(eout + (size_t)wave * DIM + q * 8);
        __builtin_nontemporal_store(lo, op);
        __builtin_nontemporal_store(hi, op + 1);
    }
}

// layer-3: SpMM only at sampled rows (users then items), accumulate fp32 into acc
__global__ void k_samp(const ushort* __restrict__ ein, const int* __restrict__ users,
                       const int* __restrict__ items, const int* __restrict__ row_ptr,
                       const int2* __restrict__ fin, float* __restrict__ accU,
                       float* __restrict__ accI) {
    int wv = (blockIdx.x * blockDim.x + threadIdx.x) >> 6;
    if (wv >= 2 * BATCH) return;
    int lane = threadIdx.x & 63;
    int g = lane >> 3;
    int q = lane & 7;
    int node; float* accb;
    if (wv < BATCH) { node = users[wv]; accb = accU + (size_t)wv * DIM; }
    else { node = items[wv - BATCH] + N_USERS; accb = accI + (size_t)(wv - BATCH) * DIM; }
    int start = row_ptr[node], end = row_ptr[node + 1];
    float acc[8];
#pragma unroll
    for (int j = 0; j < 8; j++) acc[j] = 0.f;
    for (int e = start + g; e < end; e += 8) {
        int2 r0 = fin[e];
        SPMM_EDGE(r0);
    }
#pragma unroll
    for (int off = 8; off < 64; off <<= 1) {
#pragma unroll
        for (int j = 0; j < 8; j++) acc[j] += __shfl_xor(acc[j], off);
    }
    if (lane < 8) {
        float* row = accb + q * 8;
        float4 a0 = *(float4*)row;
        float4 a1 = *(float4*)(row + 4);
        a0.x += acc[0]; a0.y += acc[1]; a0.z += acc[2]; a0.w += acc[3];
        a1.x += acc[4]; a1.y += acc[5]; a1.z += acc[6]; a1.w += acc[7];
        *(float4*)row = a0;
        *(float4*)(row + 4) = a1;
    }
}

// layer-0: overwrite both acc buffers from fp32 input tables (single launch)
__global__ void k_gather0(const float* __restrict__ uemb, const float* __restrict__ iemb,
                          const int* __restrict__ users, const int* __restrict__ items,
                          float* __restrict__ accU, float* __restrict__ accI) {
    int i = blockIdx.x * blockDim.x + threadIdx.x;
    if (i >= 2 * BATCH * DIM) return;
    int j = (i < BATCH * DIM) ? i : i - BATCH * DIM;
    int b = j >> 6, l = j & 63;
    if (i < BATCH * DIM) accU[j] = uemb[(size_t)users[b] * DIM + l];
    else accI[j] = iemb[(size_t)items[b] * DIM + l];
}

// layers 1-2: accumulate both sample sets from bf16 table (single launch)
__global__ void k_gacc(const ushort* __restrict__ emb, const int* __restrict__ users,
                       const int* __restrict__ items, float* __restrict__ accU,
                       float* __restrict__ accI) {
    int i = blockIdx.x * blockDim.x + threadIdx.x;
    if (i >= 2 * BATCH * DIM) return;
    int j = (i < BATCH * DIM) ? i : i - BATCH * DIM;
    int b = j >> 6, l = j & 63;
    if (i < BATCH * DIM) {
        unsigned int u = emb[(size_t)users[b] * DIM + l];
        accU[j] += __uint_as_float(u << 16);
    } else {
        unsigned int u = emb[(size_t)(items[b] + N_USERS) * DIM + l];
        accI[j] += __uint_as_float(u << 16);
    }
}

__global__ void k_dot(const float* __restrict__ accU, const float* __restrict__ accI,
                      float* __restrict__ out) {
    int wave = (blockIdx.x * blockDim.x + threadIdx.x) >> 6;
    if (wave >= BATCH) return;
    int lane = threadIdx.x & 63;
    float p = accU[wave * 64 + lane] * accI[wave * 64 + lane];
    for (int off = 32; off; off >>= 1) p += __shfl_xor(p, off);
    if (lane == 0) out[wave] = p * (1.0f / 16.0f);  // (acc/4)·(acc/4)
}

// ---------------- launch ----------------

extern "C" void kernel_launch(void* const* d_in, const int* in_sizes, int n_in,
                              void* d_out, int out_size, void* d_ws, size_t ws_size,
                              hipStream_t stream) {
    const float* user_emb = (const float*)d_in[0];
    const float* item_emb = (const float*)d_in[1];
    const float* vals = (const float*)d_in[2];
    const int* src = (const int*)d_in[3];
    const int* dst = (const int*)d_in[4];
    const int* users = (const int*)d_in[5];
    const int* items = (const int*)d_in[6];
    float* out = (float*)d_out;

    char* ws = (char*)d_ws;
    size_t off = 0;
    auto alloc = [&](size_t bytes) {
        char* p = ws + off;
        off += (bytes + 255) & ~(size_t)255;
        return p;
    };
    ushort* ebf0 = (ushort*)alloc((size_t)N_NODES * DIM * 2);  // bf16 concat(input tables)
    ushort* ebf1 = (ushort*)alloc((size_t)N_NODES * DIM * 2);  // layer-1 out (aliases tmp lo)
    ushort* ebf2 = (ushort*)alloc((size_t)N_NODES * DIM * 2);  // layer-2 out (aliases tmp hi)
    int2* fin = (int2*)alloc((size_t)N_EDGES * 8);
    int* row_ptr = (int*)alloc((size_t)(N_NODES + 1) * 4);
    int* bucket_ptr = (int*)alloc((size_t)(NBKT + 1) * 4);
    int* gcur = (int*)alloc((size_t)NBKT * 4);
    float* accU = (float*)alloc((size_t)BATCH * DIM * 4);
    float* accI = (float*)alloc((size_t)BATCH * DIM * 4);
    // 37.75 MB fixed-stride partition scratch aliases ebf1+ebf2 (38.4 MB contiguous);
    // tmp is dead after k_bsort, before ebf1/2 are first written.
    int2* tmp = (int2*)ebf1;

    hipMemsetAsync(gcur, 0, (size_t)NBKT * 4, stream);

    // convert input tables to bf16 (concat layout)
    k_cvt<<<(N_NODES * DIM / 4 + 255) / 256, 256, 0, stream>>>(user_emb, item_emb, ebf0);

    // CSR build: partition into fixed-stride buckets, scan sizes, sort per bucket
    int pa_blocks = (N_EDGES + PA_EDGES - 1) / PA_EDGES;
    k_partition<<<pa_blocks, 256, 0, stream>>>(src, dst, vals, gcur, tmp);
    k_bscan<<<1, 64, 0, stream>>>(gcur, bucket_ptr);
    k_bsort<<<NBKT, 512, 0, stream>>>(tmp, gcur, bucket_ptr, row_ptr, fin);

    // layer-0 contribution straight from the fp32 input tables
    int gb = (2 * BATCH * DIM + 255) / 256;
    k_gather0<<<gb, 256, 0, stream>>>(user_emb, item_emb, users, items, accU, accI);

    int spmm_blocks = (N_NODES * 64 + 255) / 256;
    // layer 1: ebf0 -> ebf1
    k_spmm16<<<spmm_blocks, 256, 0, stream>>>(ebf0, ebf1, row_ptr, fin);
    k_gacc<<<gb, 256, 0, stream>>>(ebf1, users, items, accU, accI);
    // layer 2: ebf1 -> ebf2
    k_spmm16<<<spmm_blocks, 256, 0, stream>>>(ebf1, ebf2, row_ptr, fin);
    k_gacc<<<gb, 256, 0, stream>>>(ebf2, users, items, accU, accI);
    // layer 3: only at sampled rows, straight into acc
    k_samp<<<(2 * BATCH * 64 + 255) / 256, 256, 0, stream>>>(ebf2, users, items, row_ptr, fin,
                                                             accU, accI);

    k_dot<<<(BATCH * 64 + 255) / 256, 256, 0, stream>>>(accU, accI, out);
}